// Round 13
// baseline (174.268 us; speedup 1.0000x reference)
//
#include <hip/hip_runtime.h>
#include <hip/hip_bf16.h>

typedef __attribute__((ext_vector_type(4))) float f32x4;
typedef __attribute__((ext_vector_type(8))) short bf16x8;

#define MFMA16(A, B, C) __builtin_amdgcn_mfma_f32_16x16x32_bf16(A, B, C, 0, 0, 0)

// 2*log2(e): tanh(x) = 1 - 2/(1 + 2^(C2*x))
#define C2 2.8853900817779268f
// C2 / sqrt(128), folded into Wq/bq so MFMA output is already exp2-scaled
#define QS (2.8853900817779268f / 11.313708498984761f)

__device__ __forceinline__ unsigned cvtpk_bf16(float lo, float hi) {
    unsigned r;
    asm("v_cvt_pk_bf16_f32 %0, %1, %2" : "=v"(r) : "v"(lo), "v"(hi));
    return r;
}

__device__ __forceinline__ bf16x8 pack8(float4 a, float4 b) {
    union { unsigned u[4]; bf16x8 v; } u;
    u.u[0] = cvtpk_bf16(a.x, a.y);
    u.u[1] = cvtpk_bf16(a.z, a.w);
    u.u[2] = cvtpk_bf16(b.x, b.y);
    u.u[3] = cvtpk_bf16(b.z, b.w);
    return u.v;
}

// async global->LDS, 16B per lane; LDS dest = wave-uniform base + lane*16
__device__ __forceinline__ void gload_lds16(const void* g, void* l) {
    __builtin_amdgcn_global_load_lds(
        (const __attribute__((address_space(1))) unsigned int*)g,
        (__attribute__((address_space(3))) unsigned int*)l, 16, 0, 0);
}

// ---------------------------------------------------------------------------
// Kernel 1: transpose + convert weights to bf16, fold scales, stash biases.
// ---------------------------------------------------------------------------
__global__ void prep_weights(const float* __restrict__ Wq, const float* __restrict__ bq,
                             const float* __restrict__ Wk, const float* __restrict__ bk,
                             const float* __restrict__ Wv, const float* __restrict__ bv,
                             __hip_bfloat16* __restrict__ Wqt, __hip_bfloat16* __restrict__ Wkt,
                             __hip_bfloat16* __restrict__ Wvt, float* __restrict__ bias) {
    int i = blockIdx.x * 256 + threadIdx.x;  // 64 blocks * 256 = 16384 exactly
    int k = i >> 7, o = i & 127;
    Wqt[o * 128 + k] = __float2bfloat16(Wq[i] * QS);
    Wkt[o * 128 + k] = __float2bfloat16(Wk[i]);
    Wvt[o * 128 + k] = __float2bfloat16(Wv[i] * 0.25f);  // head-mean folded into V
    if (i < 128) {
        bias[i]       = bq[i] * QS;
        bias[128 + i] = bk[i];
        bias[256 + i] = bv[i] * 0.25f;
    }
}

// ---------------------------------------------------------------------------
// Kernel 2: Q/K/V projections via 16x16x32 bf16 MFMA.
//   Qo, Ko: row-major [B*N][128] bf16 (Q pre-scaled by C2/sqrt(128))
//   Vt:     transposed [B][128][N] bf16 (pre-scaled by 0.25)
// ---------------------------------------------------------------------------
__global__ __launch_bounds__(256) void proj_qkv(
        const float* __restrict__ x, const float* __restrict__ cond,
        const __hip_bfloat16* __restrict__ Wqt, const __hip_bfloat16* __restrict__ Wkt,
        const __hip_bfloat16* __restrict__ Wvt, const float* __restrict__ bias,
        __hip_bfloat16* __restrict__ Qo, __hip_bfloat16* __restrict__ Ko,
        __hip_bfloat16* __restrict__ Vt) {
    const int lane = threadIdx.x & 63, wv = threadIdx.x >> 6;
    const int l15 = lane & 15, g = lane >> 4;
    const int row0 = blockIdx.x * 64 + wv * 16;   // 256 blocks x 64 rows

    f32x4 qa[8], ka[8], va[8];
#pragma unroll
    for (int ot = 0; ot < 8; ++ot) {
        float b0 = bias[16 * ot + l15];
        float b1 = bias[128 + 16 * ot + l15];
        float b2 = bias[256 + 16 * ot + l15];
        qa[ot] = (f32x4){b0, b0, b0, b0};
        ka[ot] = (f32x4){b1, b1, b1, b1};
        va[ot] = (f32x4){b2, b2, b2, b2};
    }

    const float* xp = x    + (size_t)(row0 + l15) * 128 + 8 * g;
    const float* cp = cond + (size_t)(row0 + l15) * 128 + 8 * g;
#pragma unroll
    for (int kk = 0; kk < 4; ++kk) {
        float4 x0 = *(const float4*)(xp + 32 * kk);
        float4 x1 = *(const float4*)(xp + 32 * kk + 4);
        float4 c0 = *(const float4*)(cp + 32 * kk);
        float4 c1 = *(const float4*)(cp + 32 * kk + 4);
        bf16x8 xa = pack8(x0, x1);
        bf16x8 ca = pack8(c0, c1);
#pragma unroll
        for (int ot = 0; ot < 8; ++ot) {
            const int wo = (16 * ot + l15) * 128 + 32 * kk + 8 * g;
            qa[ot] = MFMA16(xa, *(const bf16x8*)(Wqt + wo), qa[ot]);
            ka[ot] = MFMA16(ca, *(const bf16x8*)(Wkt + wo), ka[ot]);
            va[ot] = MFMA16(ca, *(const bf16x8*)(Wvt + wo), va[ot]);
        }
    }

    // Q, K row-major stores (C/D layout: row = 4g+r, col = 16ot+l15)
#pragma unroll
    for (int ot = 0; ot < 8; ++ot)
#pragma unroll
        for (int r = 0; r < 4; ++r) {
            size_t idx = (size_t)(row0 + 4 * g + r) * 128 + 16 * ot + l15;
            Qo[idx] = __float2bfloat16(qa[ot][r]);
            Ko[idx] = __float2bfloat16(ka[ot][r]);
        }
    // V transposed store: lane holds 4 consecutive n for fixed d -> dwordx2
    const int bb = row0 >> 11, nn = (row0 & 2047) + 4 * g;
#pragma unroll
    for (int ot = 0; ot < 8; ++ot) {
        uint2 pr;
        pr.x = cvtpk_bf16(va[ot][0], va[ot][1]);
        pr.y = cvtpk_bf16(va[ot][2], va[ot][3]);
        *(uint2*)((unsigned short*)Vt + ((size_t)bb * 128 + 16 * ot + l15) * 2048 + nn) = pr;
    }
}

// ---------------------------------------------------------------------------
// Kernel 3: fused tanh-attention, register-P pipeline (R13).
// R6-R12 post-mortem: time pinned at ~76-90 us across all sync variants; the
// invariant was the A-tile LDS round-trip + mid-chunk block-wide rendezvous.
// Here P never touches LDS: swapped QK leaves P[m][q] in regs; a 4-dword
// ds_bpermute exchange (within the l15 column) builds the PV B-operand
// fragment directly; PV computes O^T = mfma(Vt_frag, P_frag) into 32
// wave-private accumulators. ONE barrier per 64-m chunk (K/V stage swap
// only). Upgraded XOR swizzles ((row&7)<<5 K, (row&3)<<5 V) hit 16 distinct
// start banks -> 4-way b128 conflicts instead of 8-way. LDS 64 KB (no A).
// Grid 512 = XCD-pinned batch (blockIdx&7) x 2 m-halves x 32 q-tiles.
// ---------------------------------------------------------------------------
__global__ __launch_bounds__(512) void attn_main(
        const __hip_bfloat16* __restrict__ Q, const __hip_bfloat16* __restrict__ K,
        const __hip_bfloat16* __restrict__ Vt, const float* __restrict__ mask,
        float* __restrict__ out) {
    __shared__ __align__(16) char Kl[2][16384];   // [64 m][256B] per buf
    __shared__ __align__(16) char Vl[2][16384];   // [128 d][128B] per buf

    const int lane = threadIdx.x & 63, w = threadIdx.x >> 6;
    const int l15 = lane & 15, g = lane >> 4;
    const int qw = w & 3, mw = w >> 2;
    // XCD-pinned decomposition: batch = blockIdx & 7 (== XCD under round-robin)
    const int b  = blockIdx.x & 7;
    const int r2 = blockIdx.x >> 3;
    const int qt = r2 & 31;
    const int mh = r2 >> 5;
    const int n0 = qt * 64;
    const int mh0 = mh * 1024;

    const __hip_bfloat16* Qb = Q + ((size_t)b * 2048 + n0 + qw * 16) * 128;
    const char* Kg = (const char*)(K + (size_t)b * 2048 * 128);
    const char* Vg = (const char*)(Vt + (size_t)b * 128 * 2048);
    // lane's mask base: q-row (n0+qw*16+l15), m = mh0 + mw*32 + 4g
    const float* mrow = mask + ((size_t)b * 2048 + n0 + qw * 16 + l15) * 2048
                        + mh0 + mw * 32 + 4 * g;

    bf16x8 qf[4];
#pragma unroll
    for (int h = 0; h < 4; ++h)
        qf[h] = *(const bf16x8*)(Qb + l15 * 128 + 32 * h + 8 * g);

    f32x4 oacc[8];   // O^T: oacc[dt][r] = O[q=l15][d = dt*16 + 4g + r]
#pragma unroll
    for (int dt = 0; dt < 8; ++dt) oacc[dt] = (f32x4){0.f, 0.f, 0.f, 0.f};
    const f32x4 zero = (f32x4){0.f, 0.f, 0.f, 0.f};

    // bpermute indices for the P exchange (loop-invariant):
    // af dwords {0,1} come from quad 2g   -> src lane l15 + 16*((2g)&3)
    // af dwords {2,3} come from quad 2g+1 -> src lane l15 + 16*((2g+1)&3)
    const int idxA = (l15 + 16 * ((2 * g) & 3)) * 4;
    const int idxB = (l15 + 16 * ((2 * g + 1) & 3)) * 4;
    const bool lowg = (g < 2);   // quads 2g,2g+1 < 4 -> source tile st=0

    // staging: 2 K-instr + 2 V-instr per wave (1 KB each, linear LDS dest,
    // XOR-swizzled global source; reads apply the same XOR -- rule #21)
    auto STAGE = [&](int m0g, int bi) {
#pragma unroll
        for (int i = 0; i < 2; ++i) {
            const int t = w * 2 + i;
            const int o = t * 1024 + lane * 16;
            const int kr = o >> 8, kc = o & 255;
            gload_lds16(Kg + (size_t)(m0g + kr) * 256 + (kc ^ ((kr & 7) << 5)),
                        &Kl[bi][t * 1024]);
            const int vr = o >> 7, vc = o & 127;
            gload_lds16(Vg + (size_t)vr * 4096 + (size_t)m0g * 2 + (vc ^ ((vr & 3) << 5)),
                        &Vl[bi][t * 1024]);
        }
    };

    // prologue: stage chunk 0, load chunk-0 mask
    STAGE(mh0, 0);
    f32x4 mkc0 = *(const f32x4*)(mrow);
    f32x4 mkc1 = *(const f32x4*)(mrow + 16);
    asm volatile("s_waitcnt vmcnt(0)" ::: "memory");
    __builtin_amdgcn_s_barrier();

#pragma unroll 2
    for (int c = 0; c < 16; ++c) {
        const int bi = c & 1;
        // issue next chunk's stage + mask prefetch (in flight all chunk)
        if (c < 15) STAGE(mh0 + (c + 1) * 64, bi ^ 1);
        f32x4 mkn0, mkn1;
        if (c < 15) {
            mkn0 = *(const f32x4*)(mrow + (c + 1) * 64);
            mkn1 = *(const f32x4*)(mrow + (c + 1) * 64 + 16);
        }

        // ---- QK + tanh (wave's 16q x 32m), P stays in registers ----
        unsigned tx[2], ty[2];
#pragma unroll
        for (int st = 0; st < 2; ++st) {
            const int mr = mw * 32 + st * 16 + l15;   // K row within chunk
            const char* kb = &Kl[bi][mr * 256];
            const int sw = (mr & 7) << 5;
            f32x4 s0 = MFMA16(*(const bf16x8*)(kb + ((g * 16) ^ sw)),       qf[0], zero);
            f32x4 s1 = MFMA16(*(const bf16x8*)(kb + ((64 + g * 16) ^ sw)),  qf[1], zero);
            f32x4 s2 = MFMA16(*(const bf16x8*)(kb + ((128 + g * 16) ^ sw)), qf[2], zero);
            f32x4 s3 = MFMA16(*(const bf16x8*)(kb + ((192 + g * 16) ^ sw)), qf[3], zero);
            const f32x4 mk = st ? mkc1 : mkc0;
            float acd[4];
#pragma unroll
            for (int r = 0; r < 4; ++r) {
                float m2 = mk[r] * C2;
                float e0 = __builtin_amdgcn_exp2f(m2 + s0[r]);
                float e1 = __builtin_amdgcn_exp2f(m2 + s1[r]);
                float e2 = __builtin_amdgcn_exp2f(m2 + s2[r]);
                float e3 = __builtin_amdgcn_exp2f(m2 + s3[r]);
                float rs = __builtin_amdgcn_rcpf(1.f + e0) + __builtin_amdgcn_rcpf(1.f + e1)
                         + __builtin_amdgcn_rcpf(1.f + e2) + __builtin_amdgcn_rcpf(1.f + e3);
                acd[r] = 4.f - 2.f * rs;   // sum_h tanh(...)
            }
            // lane holds P quad (4st+g): m = st*16 + 4g + {0..3}, q = l15
            tx[st] = cvtpk_bf16(acd[0], acd[1]);
            ty[st] = cvtpk_bf16(acd[2], acd[3]);
        }

        // ---- exchange: build PV B-operand P[q=l15][m 8g..8g+7] ----
        union { unsigned u[4]; bf16x8 v; } af;
        {
            unsigned a0 = __builtin_amdgcn_ds_bpermute(idxA, (int)tx[0]);
            unsigned b0 = __builtin_amdgcn_ds_bpermute(idxA, (int)tx[1]);
            unsigned a1 = __builtin_amdgcn_ds_bpermute(idxA, (int)ty[0]);
            unsigned b1 = __builtin_amdgcn_ds_bpermute(idxA, (int)ty[1]);
            unsigned a2 = __builtin_amdgcn_ds_bpermute(idxB, (int)tx[0]);
            unsigned b2 = __builtin_amdgcn_ds_bpermute(idxB, (int)tx[1]);
            unsigned a3 = __builtin_amdgcn_ds_bpermute(idxB, (int)ty[0]);
            unsigned b3 = __builtin_amdgcn_ds_bpermute(idxB, (int)ty[1]);
            af.u[0] = lowg ? a0 : b0;
            af.u[1] = lowg ? a1 : b1;
            af.u[2] = lowg ? a2 : b2;
            af.u[3] = lowg ? a3 : b3;
        }

        // ---- PV: O^T += mfma(Vt_frag, P_frag) over wave's 32 m ----
#pragma unroll
        for (int dt = 0; dt < 8; ++dt) {
            const int dr = dt * 16 + l15;
            bf16x8 vf = *(const bf16x8*)(
                &Vl[bi][dr * 128 + ((mw * 64 + g * 16) ^ ((dr & 3) << 5))]);
            oacc[dt] = MFMA16(vf, af.v, oacc[dt]);
        }

        // ONE barrier/chunk: own stage drained; all waves' reads of bi done
        asm volatile("s_waitcnt vmcnt(0)" ::: "memory");
        __builtin_amdgcn_s_barrier();

        mkc0 = mkn0;
        mkc1 = mkn1;
    }

    // epilogue: per-wave 16q x 128d (O^T regs) -> atomics; contenders =
    // 2 mw waves x 2 m-half blocks = 4 per address.
    float* ob = out + ((size_t)b * 2048 + n0 + qw * 16 + l15) * 128;
#pragma unroll
    for (int dt = 0; dt < 8; ++dt)
#pragma unroll
        for (int r = 0; r < 4; ++r)
            unsafeAtomicAdd(&ob[dt * 16 + 4 * g + r], oacc[dt][r]);
}

// ---------------------------------------------------------------------------
extern "C" void kernel_launch(void* const* d_in, const int* in_sizes, int n_in,
                              void* d_out, int out_size, void* d_ws, size_t ws_size,
                              hipStream_t stream) {
    const float* x    = (const float*)d_in[0];
    const float* cond = (const float*)d_in[1];
    // d_in[2] = flags (unused by reference)
    const float* mask = (const float*)d_in[3];
    const float* Wq = (const float*)d_in[4];
    const float* bq = (const float*)d_in[5];
    const float* Wk = (const float*)d_in[6];
    const float* bk = (const float*)d_in[7];
    const float* Wv = (const float*)d_in[8];
    const float* bv = (const float*)d_in[9];
    float* out = (float*)d_out;

    char* ws = (char*)d_ws;
    __hip_bfloat16* Qo  = (__hip_bfloat16*)(ws);                       // 4 MB
    __hip_bfloat16* Ko  = (__hip_bfloat16*)(ws + (4  << 20));          // 4 MB
    __hip_bfloat16* Vt  = (__hip_bfloat16*)(ws + (8  << 20));          // 4 MB
    __hip_bfloat16* Wqt = (__hip_bfloat16*)(ws + (12 << 20));          // 32 KB
    __hip_bfloat16* Wkt = (__hip_bfloat16*)(ws + (12 << 20) + 32768);
    __hip_bfloat16* Wvt = (__hip_bfloat16*)(ws + (12 << 20) + 65536);
    float*          bias = (float*)(ws + (12 << 20) + 98304);          // 1.5 KB

    // out accumulates atomic partials -> zero it first
    hipMemsetAsync(d_out, 0, (size_t)out_size * sizeof(float), stream);

    prep_weights<<<64, 256, 0, stream>>>(Wq, bq, Wk, bk, Wv, bv, Wqt, Wkt, Wvt, bias);
    proj_qkv<<<256, 256, 0, stream>>>(x, cond, Wqt, Wkt, Wvt, bias, Qo, Ko, Vt);
    attn_main<<<512, 512, 0, stream>>>(Qo, Ko, Vt, mask, out);
}

// Round 14
// 134.757 us; speedup vs baseline: 1.2932x; 1.2932x over previous
//
#include <hip/hip_runtime.h>
#include <hip/hip_bf16.h>

typedef __attribute__((ext_vector_type(4))) float f32x4;
typedef __attribute__((ext_vector_type(8))) short bf16x8;

#define MFMA16(A, B, C) __builtin_amdgcn_mfma_f32_16x16x32_bf16(A, B, C, 0, 0, 0)

// 2*log2(e): tanh(x) = 1 - 2/(1 + 2^(C2*x))
#define C2 2.8853900817779268f
// C2 / sqrt(128), folded into Wq/bq so MFMA output is already exp2-scaled
#define QS (2.8853900817779268f / 11.313708498984761f)

__device__ __forceinline__ unsigned cvtpk_bf16(float lo, float hi) {
    unsigned r;
    asm("v_cvt_pk_bf16_f32 %0, %1, %2" : "=v"(r) : "v"(lo), "v"(hi));
    return r;
}

__device__ __forceinline__ bf16x8 pack8(float4 a, float4 b) {
    union { unsigned u[4]; bf16x8 v; } u;
    u.u[0] = cvtpk_bf16(a.x, a.y);
    u.u[1] = cvtpk_bf16(a.z, a.w);
    u.u[2] = cvtpk_bf16(b.x, b.y);
    u.u[3] = cvtpk_bf16(b.z, b.w);
    return u.v;
}

// async global->LDS, 16B per lane; LDS dest = wave-uniform base + lane*16
__device__ __forceinline__ void gload_lds16(const void* g, void* l) {
    __builtin_amdgcn_global_load_lds(
        (const __attribute__((address_space(1))) unsigned int*)g,
        (__attribute__((address_space(3))) unsigned int*)l, 16, 0, 0);
}

// ---------------------------------------------------------------------------
// Kernel 1: transpose + convert weights to bf16, fold scales, stash biases.
// ---------------------------------------------------------------------------
__global__ void prep_weights(const float* __restrict__ Wq, const float* __restrict__ bq,
                             const float* __restrict__ Wk, const float* __restrict__ bk,
                             const float* __restrict__ Wv, const float* __restrict__ bv,
                             __hip_bfloat16* __restrict__ Wqt, __hip_bfloat16* __restrict__ Wkt,
                             __hip_bfloat16* __restrict__ Wvt, float* __restrict__ bias) {
    int i = blockIdx.x * 256 + threadIdx.x;  // 64 blocks * 256 = 16384 exactly
    int k = i >> 7, o = i & 127;
    Wqt[o * 128 + k] = __float2bfloat16(Wq[i] * QS);
    Wkt[o * 128 + k] = __float2bfloat16(Wk[i]);
    Wvt[o * 128 + k] = __float2bfloat16(Wv[i] * 0.25f);  // head-mean folded into V
    if (i < 128) {
        bias[i]       = bq[i] * QS;
        bias[128 + i] = bk[i];
        bias[256 + i] = bv[i] * 0.25f;
    }
}

// ---------------------------------------------------------------------------
// Kernel 2: Q/K/V projections via 16x16x32 bf16 MFMA.
//   Qo, Ko: row-major [B*N][128] bf16 (Q pre-scaled by C2/sqrt(128))
//   Vt:     transposed [B][128][N] bf16 (pre-scaled by 0.25)
// ---------------------------------------------------------------------------
__global__ __launch_bounds__(256) void proj_qkv(
        const float* __restrict__ x, const float* __restrict__ cond,
        const __hip_bfloat16* __restrict__ Wqt, const __hip_bfloat16* __restrict__ Wkt,
        const __hip_bfloat16* __restrict__ Wvt, const float* __restrict__ bias,
        __hip_bfloat16* __restrict__ Qo, __hip_bfloat16* __restrict__ Ko,
        __hip_bfloat16* __restrict__ Vt) {
    const int lane = threadIdx.x & 63, wv = threadIdx.x >> 6;
    const int l15 = lane & 15, g = lane >> 4;
    const int row0 = blockIdx.x * 64 + wv * 16;   // 256 blocks x 64 rows

    f32x4 qa[8], ka[8], va[8];
#pragma unroll
    for (int ot = 0; ot < 8; ++ot) {
        float b0 = bias[16 * ot + l15];
        float b1 = bias[128 + 16 * ot + l15];
        float b2 = bias[256 + 16 * ot + l15];
        qa[ot] = (f32x4){b0, b0, b0, b0};
        ka[ot] = (f32x4){b1, b1, b1, b1};
        va[ot] = (f32x4){b2, b2, b2, b2};
    }

    const float* xp = x    + (size_t)(row0 + l15) * 128 + 8 * g;
    const float* cp = cond + (size_t)(row0 + l15) * 128 + 8 * g;
#pragma unroll
    for (int kk = 0; kk < 4; ++kk) {
        float4 x0 = *(const float4*)(xp + 32 * kk);
        float4 x1 = *(const float4*)(xp + 32 * kk + 4);
        float4 c0 = *(const float4*)(cp + 32 * kk);
        float4 c1 = *(const float4*)(cp + 32 * kk + 4);
        bf16x8 xa = pack8(x0, x1);
        bf16x8 ca = pack8(c0, c1);
#pragma unroll
        for (int ot = 0; ot < 8; ++ot) {
            const int wo = (16 * ot + l15) * 128 + 32 * kk + 8 * g;
            qa[ot] = MFMA16(xa, *(const bf16x8*)(Wqt + wo), qa[ot]);
            ka[ot] = MFMA16(ca, *(const bf16x8*)(Wkt + wo), ka[ot]);
            va[ot] = MFMA16(ca, *(const bf16x8*)(Wvt + wo), va[ot]);
        }
    }

    // Q, K row-major stores (C/D layout: row = 4g+r, col = 16ot+l15)
#pragma unroll
    for (int ot = 0; ot < 8; ++ot)
#pragma unroll
        for (int r = 0; r < 4; ++r) {
            size_t idx = (size_t)(row0 + 4 * g + r) * 128 + 16 * ot + l15;
            Qo[idx] = __float2bfloat16(qa[ot][r]);
            Ko[idx] = __float2bfloat16(ka[ot][r]);
        }
    // V transposed store: lane holds 4 consecutive n for fixed d -> dwordx2
    const int bb = row0 >> 11, nn = (row0 & 2047) + 4 * g;
#pragma unroll
    for (int ot = 0; ot < 8; ++ot) {
        uint2 pr;
        pr.x = cvtpk_bf16(va[ot][0], va[ot][1]);
        pr.y = cvtpk_bf16(va[ot][2], va[ot][3]);
        *(uint2*)((unsigned short*)Vt + ((size_t)bb * 128 + 16 * ot + l15) * 2048 + nn) = pr;
    }
}

// ---------------------------------------------------------------------------
// Kernel 3: fused tanh-attention (R14 = R12 - V_lds + 3 blocks/CU + setprio).
// R13 post-mortem: register-P exchange regressed on uncoalesced atomic
// epilogue; reverted to R12 structure. R14 changes vs R12 (76 us):
//  - V read DIRECTLY from global during PV: with XCD-pinned batches (R12),
//    each XCD's V slice (1 MB) is L2-resident, so the R7 regression cause
//    (cross-XCD L2 thrash) is gone. Drops Vl -> LDS 42 KB -> 3 blocks/CU.
//  - grid 1024 (4-way m-split, 512 m/block, 8 chunks of 64 m) to fill the
//    3-blocks/CU residency (24 waves/CU, +50% TLP over R12).
//  - T5: s_setprio(1) around the PV MFMA cluster (phase-split schedule).
// ---------------------------------------------------------------------------
__global__ __launch_bounds__(512) void attn_main(
        const __hip_bfloat16* __restrict__ Q, const __hip_bfloat16* __restrict__ K,
        const __hip_bfloat16* __restrict__ Vt, const float* __restrict__ mask,
        float* __restrict__ out) {
    __shared__ __align__(16) char Kl[2][16384];   // [64 m][256B] per buf
    __shared__ __align__(16) char Al[64 * 144];   // [64 q][72 bf16]

    const int lane = threadIdx.x & 63, w = threadIdx.x >> 6;
    const int l15 = lane & 15, g = lane >> 4;
    const int qw = w & 3, mw = w >> 2, dw = mw;
    // XCD-pinned decomposition: batch = blockIdx & 7 (== XCD under round-robin)
    const int b  = blockIdx.x & 7;
    const int r2 = blockIdx.x >> 3;
    const int qt = r2 & 31;
    const int mq = r2 >> 5;            // 0..3: m-quarter
    const int n0 = qt * 64;
    const int mq0 = mq * 512;

    const __hip_bfloat16* Qb = Q + ((size_t)b * 2048 + n0 + qw * 16) * 128;
    const char* Kg = (const char*)(K + (size_t)b * 2048 * 128);
    const char* Vg = (const char*)(Vt + (size_t)b * 128 * 2048);
    const float* mrow = mask + ((size_t)b * 2048 + n0 + qw * 16 + l15) * 2048
                        + mq0 + mw * 32 + 4 * g;

    bf16x8 qf[4];
#pragma unroll
    for (int h = 0; h < 4; ++h)
        qf[h] = *(const bf16x8*)(Qb + l15 * 128 + 32 * h + 8 * g);

    f32x4 oacc[4];
#pragma unroll
    for (int dtl = 0; dtl < 4; ++dtl) oacc[dtl] = (f32x4){0.f, 0.f, 0.f, 0.f};
    const f32x4 zero = (f32x4){0.f, 0.f, 0.f, 0.f};

    // K staging: 2 instr/wave (1 KB each, linear LDS dest, swizzled source)
    auto STAGE_K = [&](int m0g, int bi) {
#pragma unroll
        for (int i = 0; i < 2; ++i) {
            const int t = w * 2 + i;
            const int o = t * 1024 + lane * 16;
            const int kr = o >> 8, kc = o & 255;
            gload_lds16(Kg + (size_t)(m0g + kr) * 256 + (kc ^ ((kr & 7) << 4)),
                        &Kl[bi][t * 1024]);
        }
    };

    // prologue: stage chunk 0, prefetch mask chunk 0
    STAGE_K(mq0, 0);
    f32x4 mkc0 = *(const f32x4*)(mrow);
    f32x4 mkc1 = *(const f32x4*)(mrow + 16);
    asm volatile("s_waitcnt vmcnt(0)" ::: "memory");
    __builtin_amdgcn_s_barrier();

#pragma unroll 2
    for (int c = 0; c < 8; ++c) {
        const int bi = c & 1;
        const int m0g = mq0 + c * 64;
        // issue next chunk's K stage + mask prefetch (in flight all chunk)
        if (c < 7) STAGE_K(m0g + 64, bi ^ 1);
        f32x4 mkn0, mkn1;
        if (c < 7) {
            mkn0 = *(const f32x4*)(mrow + (c + 1) * 64);
            mkn1 = *(const f32x4*)(mrow + (c + 1) * 64 + 16);
        }

        // ---- QK + tanh + A-write (wave's 16q x 32m) ----
#pragma unroll
        for (int st = 0; st < 2; ++st) {
            const int mr = mw * 32 + st * 16 + l15;
            const char* kb = &Kl[bi][mr * 256];
            const int sw = (mr & 7) << 4;
            f32x4 s0 = MFMA16(*(const bf16x8*)(kb + ((g * 16) ^ sw)),       qf[0], zero);
            f32x4 s1 = MFMA16(*(const bf16x8*)(kb + ((64 + g * 16) ^ sw)),  qf[1], zero);
            f32x4 s2 = MFMA16(*(const bf16x8*)(kb + ((128 + g * 16) ^ sw)), qf[2], zero);
            f32x4 s3 = MFMA16(*(const bf16x8*)(kb + ((192 + g * 16) ^ sw)), qf[3], zero);
            const f32x4 mk = st ? mkc1 : mkc0;
            float acd[4];
#pragma unroll
            for (int r = 0; r < 4; ++r) {
                float m2 = mk[r] * C2;
                float e0 = __builtin_amdgcn_exp2f(m2 + s0[r]);
                float e1 = __builtin_amdgcn_exp2f(m2 + s1[r]);
                float e2 = __builtin_amdgcn_exp2f(m2 + s2[r]);
                float e3 = __builtin_amdgcn_exp2f(m2 + s3[r]);
                float rs = __builtin_amdgcn_rcpf(1.f + e0) + __builtin_amdgcn_rcpf(1.f + e1)
                         + __builtin_amdgcn_rcpf(1.f + e2) + __builtin_amdgcn_rcpf(1.f + e3);
                acd[r] = 4.f - 2.f * rs;   // sum_h tanh(...)
            }
            uint2 pk;
            pk.x = cvtpk_bf16(acd[0], acd[1]);
            pk.y = cvtpk_bf16(acd[2], acd[3]);
            *(uint2*)(Al + (qw * 16 + l15) * 144 + (mw * 32 + st * 16 + 4 * g) * 2) = pk;
        }

        // A visible block-wide; K stage stays in flight (no vmcnt here)
        asm volatile("s_waitcnt lgkmcnt(0)" ::: "memory");
        __builtin_amdgcn_s_barrier();

        // ---- PV: wave's 16q x 64d over this chunk's 64 m; V from L2 ----
        __builtin_amdgcn_s_setprio(1);
#pragma unroll
        for (int ks = 0; ks < 2; ++ks) {
            bf16x8 af = *(const bf16x8*)(Al + (qw * 16 + l15) * 144 + (ks * 32 + 8 * g) * 2);
#pragma unroll
            for (int dtl = 0; dtl < 4; ++dtl) {
                const int dr = dw * 64 + dtl * 16 + l15;
                bf16x8 vf = *(const bf16x8*)(
                    Vg + (size_t)dr * 4096 + (size_t)(m0g + ks * 32 + 8 * g) * 2);
                oacc[dtl] = MFMA16(af, vf, oacc[dtl]);
            }
        }
        __builtin_amdgcn_s_setprio(0);

        // own K stage drained + everyone's A/K reads done -> swap buffers
        asm volatile("s_waitcnt vmcnt(0)" ::: "memory");
        __builtin_amdgcn_s_barrier();

        mkc0 = mkn0;
        mkc1 = mkn1;
    }

    // epilogue: per-wave-disjoint 16q x 64d tile, l15-consecutive (coalesced)
    // atomics; 4 m-quarter blocks contend per address.
    float* ob = out + ((size_t)b * 2048 + n0 + qw * 16) * 128 + dw * 64;
#pragma unroll
    for (int dtl = 0; dtl < 4; ++dtl)
#pragma unroll
        for (int r = 0; r < 4; ++r)
            unsafeAtomicAdd(&ob[(size_t)(4 * g + r) * 128 + dtl * 16 + l15], oacc[dtl][r]);
}

// ---------------------------------------------------------------------------
extern "C" void kernel_launch(void* const* d_in, const int* in_sizes, int n_in,
                              void* d_out, int out_size, void* d_ws, size_t ws_size,
                              hipStream_t stream) {
    const float* x    = (const float*)d_in[0];
    const float* cond = (const float*)d_in[1];
    // d_in[2] = flags (unused by reference)
    const float* mask = (const float*)d_in[3];
    const float* Wq = (const float*)d_in[4];
    const float* bq = (const float*)d_in[5];
    const float* Wk = (const float*)d_in[6];
    const float* bk = (const float*)d_in[7];
    const float* Wv = (const float*)d_in[8];
    const float* bv = (const float*)d_in[9];
    float* out = (float*)d_out;

    char* ws = (char*)d_ws;
    __hip_bfloat16* Qo  = (__hip_bfloat16*)(ws);                       // 4 MB
    __hip_bfloat16* Ko  = (__hip_bfloat16*)(ws + (4  << 20));          // 4 MB
    __hip_bfloat16* Vt  = (__hip_bfloat16*)(ws + (8  << 20));          // 4 MB
    __hip_bfloat16* Wqt = (__hip_bfloat16*)(ws + (12 << 20));          // 32 KB
    __hip_bfloat16* Wkt = (__hip_bfloat16*)(ws + (12 << 20) + 32768);
    __hip_bfloat16* Wvt = (__hip_bfloat16*)(ws + (12 << 20) + 65536);
    float*          bias = (float*)(ws + (12 << 20) + 98304);          // 1.5 KB

    // out accumulates atomic partials from 4 m-quarter blocks -> zero first
    hipMemsetAsync(d_out, 0, (size_t)out_size * sizeof(float), stream);

    prep_weights<<<64, 256, 0, stream>>>(Wq, bq, Wk, bk, Wv, bv, Wqt, Wkt, Wvt, bias);
    proj_qkv<<<256, 256, 0, stream>>>(x, cond, Wqt, Wkt, Wvt, bias, Qo, Ko, Vt);
    attn_main<<<1024, 512, 0, stream>>>(Qo, Ko, Vt, mask, out);
}

// Round 15
// 92.707 us; speedup vs baseline: 1.8798x; 1.4536x over previous
//
#include <hip/hip_runtime.h>
#include <hip/hip_bf16.h>

typedef __attribute__((ext_vector_type(4))) float f32x4;
typedef __attribute__((ext_vector_type(8))) short bf16x8;

#define MFMA16(A, B, C) __builtin_amdgcn_mfma_f32_16x16x32_bf16(A, B, C, 0, 0, 0)

// 2*log2(e): tanh(x) = 1 - 2/(1 + 2^(C2*x))
#define C2 2.8853900817779268f
// C2 / sqrt(128), folded into Wq/bq so MFMA output is already exp2-scaled
#define QS (2.8853900817779268f / 11.313708498984761f)

__device__ __forceinline__ unsigned cvtpk_bf16(float lo, float hi) {
    unsigned r;
    asm("v_cvt_pk_bf16_f32 %0, %1, %2" : "=v"(r) : "v"(lo), "v"(hi));
    return r;
}

__device__ __forceinline__ bf16x8 pack8(float4 a, float4 b) {
    union { unsigned u[4]; bf16x8 v; } u;
    u.u[0] = cvtpk_bf16(a.x, a.y);
    u.u[1] = cvtpk_bf16(a.z, a.w);
    u.u[2] = cvtpk_bf16(b.x, b.y);
    u.u[3] = cvtpk_bf16(b.z, b.w);
    return u.v;
}

// async global->LDS, 16B per lane; LDS dest = wave-uniform base + lane*16
__device__ __forceinline__ void gload_lds16(const void* g, void* l) {
    __builtin_amdgcn_global_load_lds(
        (const __attribute__((address_space(1))) unsigned int*)g,
        (__attribute__((address_space(3))) unsigned int*)l, 16, 0, 0);
}

// ---------------------------------------------------------------------------
// Kernel 1: transpose + convert weights to bf16, fold scales, stash biases.
// ---------------------------------------------------------------------------
__global__ void prep_weights(const float* __restrict__ Wq, const float* __restrict__ bq,
                             const float* __restrict__ Wk, const float* __restrict__ bk,
                             const float* __restrict__ Wv, const float* __restrict__ bv,
                             __hip_bfloat16* __restrict__ Wqt, __hip_bfloat16* __restrict__ Wkt,
                             __hip_bfloat16* __restrict__ Wvt, float* __restrict__ bias) {
    int i = blockIdx.x * 256 + threadIdx.x;  // 64 blocks * 256 = 16384 exactly
    int k = i >> 7, o = i & 127;
    Wqt[o * 128 + k] = __float2bfloat16(Wq[i] * QS);
    Wkt[o * 128 + k] = __float2bfloat16(Wk[i]);
    Wvt[o * 128 + k] = __float2bfloat16(Wv[i] * 0.25f);  // head-mean folded into V
    if (i < 128) {
        bias[i]       = bq[i] * QS;
        bias[128 + i] = bk[i];
        bias[256 + i] = bv[i] * 0.25f;
    }
}

// ---------------------------------------------------------------------------
// Kernel 2: Q/K/V projections via 16x16x32 bf16 MFMA.
//   Qo, Ko: row-major [B*N][128] bf16 (Q pre-scaled by C2/sqrt(128))
//   Vt:     transposed [B][128][N] bf16 (pre-scaled by 0.25)
// ---------------------------------------------------------------------------
__global__ __launch_bounds__(256) void proj_qkv(
        const float* __restrict__ x, const float* __restrict__ cond,
        const __hip_bfloat16* __restrict__ Wqt, const __hip_bfloat16* __restrict__ Wkt,
        const __hip_bfloat16* __restrict__ Wvt, const float* __restrict__ bias,
        __hip_bfloat16* __restrict__ Qo, __hip_bfloat16* __restrict__ Ko,
        __hip_bfloat16* __restrict__ Vt) {
    const int lane = threadIdx.x & 63, wv = threadIdx.x >> 6;
    const int l15 = lane & 15, g = lane >> 4;
    const int row0 = blockIdx.x * 64 + wv * 16;   // 256 blocks x 64 rows

    f32x4 qa[8], ka[8], va[8];
#pragma unroll
    for (int ot = 0; ot < 8; ++ot) {
        float b0 = bias[16 * ot + l15];
        float b1 = bias[128 + 16 * ot + l15];
        float b2 = bias[256 + 16 * ot + l15];
        qa[ot] = (f32x4){b0, b0, b0, b0};
        ka[ot] = (f32x4){b1, b1, b1, b1};
        va[ot] = (f32x4){b2, b2, b2, b2};
    }

    const float* xp = x    + (size_t)(row0 + l15) * 128 + 8 * g;
    const float* cp = cond + (size_t)(row0 + l15) * 128 + 8 * g;
#pragma unroll
    for (int kk = 0; kk < 4; ++kk) {
        float4 x0 = *(const float4*)(xp + 32 * kk);
        float4 x1 = *(const float4*)(xp + 32 * kk + 4);
        float4 c0 = *(const float4*)(cp + 32 * kk);
        float4 c1 = *(const float4*)(cp + 32 * kk + 4);
        bf16x8 xa = pack8(x0, x1);
        bf16x8 ca = pack8(c0, c1);
#pragma unroll
        for (int ot = 0; ot < 8; ++ot) {
            const int wo = (16 * ot + l15) * 128 + 32 * kk + 8 * g;
            qa[ot] = MFMA16(xa, *(const bf16x8*)(Wqt + wo), qa[ot]);
            ka[ot] = MFMA16(ca, *(const bf16x8*)(Wkt + wo), ka[ot]);
            va[ot] = MFMA16(ca, *(const bf16x8*)(Wvt + wo), va[ot]);
        }
    }

    // Q, K row-major stores (C/D layout: row = 4g+r, col = 16ot+l15)
#pragma unroll
    for (int ot = 0; ot < 8; ++ot)
#pragma unroll
        for (int r = 0; r < 4; ++r) {
            size_t idx = (size_t)(row0 + 4 * g + r) * 128 + 16 * ot + l15;
            Qo[idx] = __float2bfloat16(qa[ot][r]);
            Ko[idx] = __float2bfloat16(ka[ot][r]);
        }
    // V transposed store: lane holds 4 consecutive n for fixed d -> dwordx2
    const int bb = row0 >> 11, nn = (row0 & 2047) + 4 * g;
#pragma unroll
    for (int ot = 0; ot < 8; ++ot) {
        uint2 pr;
        pr.x = cvtpk_bf16(va[ot][0], va[ot][1]);
        pr.y = cvtpk_bf16(va[ot][2], va[ot][3]);
        *(uint2*)((unsigned short*)Vt + ((size_t)bb * 128 + 16 * ot + l15) * 2048 + nn) = pr;
    }
}

// ---------------------------------------------------------------------------
// Kernel 3a: QK^T + tanh + head-sum -> A (bf16, global) -- R15 split, part 1.
// Pure streaming: K double-buffered LDS (1 barrier/chunk); P transposed via
// WAVE-PRIVATE LDS bounce (in-wave DS ordering, no block rendezvous); A
// stored to global fully coalesced (16 rows x 64B lines per instr).
// Grid 1024 = XCD-pinned batch (blk&7) x 32 q-tiles x 4 m-quarters.
// LDS 41 KB -> 3 blocks/CU.
// ---------------------------------------------------------------------------
__global__ __launch_bounds__(512) void qk_tanh(
        const __hip_bfloat16* __restrict__ Q, const __hip_bfloat16* __restrict__ K,
        const float* __restrict__ mask, __hip_bfloat16* __restrict__ Ag) {
    __shared__ __align__(16) char Kl[2][16384];   // [64 m][256B] per buf
    __shared__ __align__(16) char Alw[8 * 1152];  // per-wave [16 q][72B]

    const int lane = threadIdx.x & 63, w = threadIdx.x >> 6;
    const int l15 = lane & 15, g = lane >> 4;
    const int qw = w & 3, mw = w >> 2;
    const int b  = blockIdx.x & 7;          // XCD-pinned batch
    const int r2 = blockIdx.x >> 3;
    const int qt = r2 & 31;                 // 32 q-tiles of 64
    const int mq = r2 >> 5;                 // 4 m-quarters of 512
    const int n0 = qt * 64;
    const int mq0 = mq * 512;

    const __hip_bfloat16* Qb = Q + ((size_t)b * 2048 + n0 + qw * 16) * 128;
    const char* Kg = (const char*)(K + (size_t)b * 2048 * 128);
    const float* mrow = mask + ((size_t)b * 2048 + n0 + qw * 16 + l15) * 2048
                        + mq0 + mw * 32 + 4 * g;
    // A store base: row q = n0+qw*16+l15, col m = mq0 + mw*32 + 8g (+ c*64)
    unsigned short* Ags = (unsigned short*)Ag + (size_t)b * 2048 * 2048
                          + (size_t)(n0 + qw * 16 + l15) * 2048 + mq0 + mw * 32 + 8 * g;
    char* Aw = Alw + w * 1152;

    bf16x8 qf[4];
#pragma unroll
    for (int h = 0; h < 4; ++h)
        qf[h] = *(const bf16x8*)(Qb + l15 * 128 + 32 * h + 8 * g);
    const f32x4 zero = (f32x4){0.f, 0.f, 0.f, 0.f};

    // K staging: 2 instr/wave (linear LDS dest, XOR-swizzled source)
    auto STAGE_K = [&](int m0g, int bi) {
#pragma unroll
        for (int i = 0; i < 2; ++i) {
            const int t = w * 2 + i;
            const int o = t * 1024 + lane * 16;
            const int kr = o >> 8, kc = o & 255;
            gload_lds16(Kg + (size_t)(m0g + kr) * 256 + (kc ^ ((kr & 7) << 4)),
                        &Kl[bi][t * 1024]);
        }
    };

    STAGE_K(mq0, 0);
    f32x4 mkc0 = *(const f32x4*)(mrow);
    f32x4 mkc1 = *(const f32x4*)(mrow + 16);
    asm volatile("s_waitcnt vmcnt(0)" ::: "memory");
    __builtin_amdgcn_s_barrier();

#pragma unroll 2
    for (int c = 0; c < 8; ++c) {
        const int bi = c & 1;
        if (c < 7) STAGE_K(mq0 + (c + 1) * 64, bi ^ 1);
        f32x4 mkn0, mkn1;
        if (c < 7) {
            mkn0 = *(const f32x4*)(mrow + (c + 1) * 64);
            mkn1 = *(const f32x4*)(mrow + (c + 1) * 64 + 16);
        }

        // ---- QK + tanh: wave's 16q x 32m -> wave-private bounce tile ----
#pragma unroll
        for (int st = 0; st < 2; ++st) {
            const int mr = mw * 32 + st * 16 + l15;
            const char* kb = &Kl[bi][mr * 256];
            const int sw = (mr & 7) << 4;
            f32x4 s0 = MFMA16(*(const bf16x8*)(kb + ((g * 16) ^ sw)),       qf[0], zero);
            f32x4 s1 = MFMA16(*(const bf16x8*)(kb + ((64 + g * 16) ^ sw)),  qf[1], zero);
            f32x4 s2 = MFMA16(*(const bf16x8*)(kb + ((128 + g * 16) ^ sw)), qf[2], zero);
            f32x4 s3 = MFMA16(*(const bf16x8*)(kb + ((192 + g * 16) ^ sw)), qf[3], zero);
            const f32x4 mk = st ? mkc1 : mkc0;
            float acd[4];
#pragma unroll
            for (int r = 0; r < 4; ++r) {
                float m2 = mk[r] * C2;
                float e0 = __builtin_amdgcn_exp2f(m2 + s0[r]);
                float e1 = __builtin_amdgcn_exp2f(m2 + s1[r]);
                float e2 = __builtin_amdgcn_exp2f(m2 + s2[r]);
                float e3 = __builtin_amdgcn_exp2f(m2 + s3[r]);
                float rs = __builtin_amdgcn_rcpf(1.f + e0) + __builtin_amdgcn_rcpf(1.f + e1)
                         + __builtin_amdgcn_rcpf(1.f + e2) + __builtin_amdgcn_rcpf(1.f + e3);
                acd[r] = 4.f - 2.f * rs;   // sum_h tanh(...)
            }
            // wave-private transpose write: row q=l15, m-local st*16+4g+0..3
            uint2 pk;
            pk.x = cvtpk_bf16(acd[0], acd[1]);
            pk.y = cvtpk_bf16(acd[2], acd[3]);
            *(uint2*)(Aw + l15 * 72 + st * 32 + 8 * g) = pk;
        }
        // in-wave DS ordering: read back own rows (no barrier needed)
        bf16x8 af = *(const bf16x8*)(Aw + l15 * 72 + 16 * g);
        *(bf16x8*)(Ags + c * 64) = af;   // coalesced: 16 rows x 64B lines

        // K swap rendezvous (only barrier in the loop)
        asm volatile("s_waitcnt vmcnt(0) lgkmcnt(0)" ::: "memory");
        __builtin_amdgcn_s_barrier();
        mkc0 = mkn0;
        mkc1 = mkn1;
    }
}

// ---------------------------------------------------------------------------
// Kernel 3b: O = A x V via tiled GEMM -- R15 split, part 2.
// Block: 32q x 128d, 16 chunks of 128 m; A-tile (8 KB) + Vt-tile (32 KB)
// double-buffered (80 KB LDS, 2 blocks/CU), 1 barrier/chunk, coalesced
// direct store (no atomics, no memset). A is L3/L2-hot from kernel 3a.
// Grid 512 = XCD-pinned batch (blk&7) x 64 q-tiles of 32.
// ---------------------------------------------------------------------------
__global__ __launch_bounds__(512) void pv_gemm(
        const __hip_bfloat16* __restrict__ Ag, const __hip_bfloat16* __restrict__ Vt,
        float* __restrict__ out) {
    __shared__ __align__(16) char Atl[2][8192];    // [32 q][256B]
    __shared__ __align__(16) char Vtl[2][32768];   // [128 d][256B]

    const int lane = threadIdx.x & 63, w = threadIdx.x >> 6;
    const int l15 = lane & 15, g = lane >> 4;
    const int qw2 = w & 1, dsub = w >> 1;
    const int b   = blockIdx.x & 7;
    const int qt2 = blockIdx.x >> 3;       // 64 q-tiles of 32
    const int n0p = qt2 * 32;

    const char* Agb = (const char*)Ag + (size_t)b * 2048 * 2048 * 2;
    const char* Vgb = (const char*)Vt + (size_t)b * 128 * 2048 * 2;

    f32x4 oacc[2];
    oacc[0] = (f32x4){0.f, 0.f, 0.f, 0.f};
    oacc[1] = (f32x4){0.f, 0.f, 0.f, 0.f};

    // staging: A 1 instr/wave, V 4 instr/wave (linear dest, swizzled source)
    auto STAGE = [&](int m0, int bi) {
        {
            const int o = w * 1024 + lane * 16;
            const int ar = o >> 8, ac = o & 255;   // 32 rows x 256B
            gload_lds16(Agb + (size_t)(n0p + ar) * 4096 + (size_t)m0 * 2
                            + (ac ^ ((ar & 7) << 4)),
                        &Atl[bi][w * 1024]);
        }
#pragma unroll
        for (int i = 0; i < 4; ++i) {
            const int t = w * 4 + i;
            const int o = t * 1024 + lane * 16;
            const int vr = o >> 8, vc = o & 255;   // 128 rows x 256B
            gload_lds16(Vgb + (size_t)vr * 4096 + (size_t)m0 * 2
                            + (vc ^ ((vr & 7) << 4)),
                        &Vtl[bi][t * 1024]);
        }
    };

    STAGE(0, 0);
    asm volatile("s_waitcnt vmcnt(0)" ::: "memory");
    __builtin_amdgcn_s_barrier();

#pragma unroll 2
    for (int c = 0; c < 16; ++c) {
        const int bi = c & 1;
        if (c < 15) STAGE((c + 1) * 128, bi ^ 1);

        const int rowq = qw2 * 16 + l15;
#pragma unroll
        for (int ks = 0; ks < 4; ++ks) {
            bf16x8 af = *(const bf16x8*)(
                &Atl[bi][rowq * 256 + ((ks * 64 + g * 16) ^ ((rowq & 7) << 4))]);
#pragma unroll
            for (int dt = 0; dt < 2; ++dt) {
                const int rowd = dsub * 32 + dt * 16 + l15;
                bf16x8 vf = *(const bf16x8*)(
                    &Vtl[bi][rowd * 256 + ((ks * 64 + g * 16) ^ ((rowd & 7) << 4))]);
                oacc[dt] = MFMA16(af, vf, oacc[dt]);
            }
        }

        asm volatile("s_waitcnt vmcnt(0) lgkmcnt(0)" ::: "memory");
        __builtin_amdgcn_s_barrier();
    }

    // coalesced direct store: D[row=4g+r -> q][col=l15 -> d]
    float* ob = out + ((size_t)b * 2048 + n0p + qw2 * 16) * 128 + dsub * 32;
#pragma unroll
    for (int dt = 0; dt < 2; ++dt)
#pragma unroll
        for (int r = 0; r < 4; ++r)
            ob[(size_t)(4 * g + r) * 128 + dt * 16 + l15] = oacc[dt][r];
}

// ---------------------------------------------------------------------------
extern "C" void kernel_launch(void* const* d_in, const int* in_sizes, int n_in,
                              void* d_out, int out_size, void* d_ws, size_t ws_size,
                              hipStream_t stream) {
    const float* x    = (const float*)d_in[0];
    const float* cond = (const float*)d_in[1];
    // d_in[2] = flags (unused by reference)
    const float* mask = (const float*)d_in[3];
    const float* Wq = (const float*)d_in[4];
    const float* bq = (const float*)d_in[5];
    const float* Wk = (const float*)d_in[6];
    const float* bk = (const float*)d_in[7];
    const float* Wv = (const float*)d_in[8];
    const float* bv = (const float*)d_in[9];
    float* out = (float*)d_out;

    char* ws = (char*)d_ws;
    __hip_bfloat16* Qo  = (__hip_bfloat16*)(ws);                       // 4 MB
    __hip_bfloat16* Ko  = (__hip_bfloat16*)(ws + (4  << 20));          // 4 MB
    __hip_bfloat16* Vt  = (__hip_bfloat16*)(ws + (8  << 20));          // 4 MB
    __hip_bfloat16* Wqt = (__hip_bfloat16*)(ws + (12 << 20));          // 32 KB
    __hip_bfloat16* Wkt = (__hip_bfloat16*)(ws + (12 << 20) + 32768);
    __hip_bfloat16* Wvt = (__hip_bfloat16*)(ws + (12 << 20) + 65536);
    float*          bias = (float*)(ws + (12 << 20) + 98304);          // 1.5 KB
    __hip_bfloat16* Ag  = (__hip_bfloat16*)(ws + (16 << 20));          // 64 MB

    prep_weights<<<64, 256, 0, stream>>>(Wq, bq, Wk, bk, Wv, bv, Wqt, Wkt, Wvt, bias);
    proj_qkv<<<256, 256, 0, stream>>>(x, cond, Wqt, Wkt, Wvt, bias, Qo, Ko, Vt);
    qk_tanh<<<1024, 512, 0, stream>>>(Qo, Ko, mask, Ag);
    pv_gemm<<<512, 512, 0, stream>>>(Ag, Vt, out);
}

// Round 16
// 87.096 us; speedup vs baseline: 2.0009x; 1.0644x over previous
//
#include <hip/hip_runtime.h>
#include <hip/hip_bf16.h>

typedef __attribute__((ext_vector_type(4))) float f32x4;
typedef __attribute__((ext_vector_type(8))) short bf16x8;

#define MFMA16(A, B, C) __builtin_amdgcn_mfma_f32_16x16x32_bf16(A, B, C, 0, 0, 0)

// 2*log2(e): tanh(x) = 1 - 2/(1 + 2^(C2*x))
#define C2 2.8853900817779268f
// C2 / sqrt(128), folded into Wq/bq so MFMA output is already exp2-scaled
#define QS (2.8853900817779268f / 11.313708498984761f)

__device__ __forceinline__ unsigned cvtpk_bf16(float lo, float hi) {
    unsigned r;
    asm("v_cvt_pk_bf16_f32 %0, %1, %2" : "=v"(r) : "v"(lo), "v"(hi));
    return r;
}

__device__ __forceinline__ bf16x8 pack8(float4 a, float4 b) {
    union { unsigned u[4]; bf16x8 v; } u;
    u.u[0] = cvtpk_bf16(a.x, a.y);
    u.u[1] = cvtpk_bf16(a.z, a.w);
    u.u[2] = cvtpk_bf16(b.x, b.y);
    u.u[3] = cvtpk_bf16(b.z, b.w);
    return u.v;
}

// async global->LDS, 16B per lane; LDS dest = wave-uniform base + lane*16
__device__ __forceinline__ void gload_lds16(const void* g, void* l) {
    __builtin_amdgcn_global_load_lds(
        (const __attribute__((address_space(1))) unsigned int*)g,
        (__attribute__((address_space(3))) unsigned int*)l, 16, 0, 0);
}

// ---------------------------------------------------------------------------
// Kernel 1: transpose + convert weights to bf16, fold scales, stash biases.
// ---------------------------------------------------------------------------
__global__ void prep_weights(const float* __restrict__ Wq, const float* __restrict__ bq,
                             const float* __restrict__ Wk, const float* __restrict__ bk,
                             const float* __restrict__ Wv, const float* __restrict__ bv,
                             __hip_bfloat16* __restrict__ Wqt, __hip_bfloat16* __restrict__ Wkt,
                             __hip_bfloat16* __restrict__ Wvt, float* __restrict__ bias) {
    int i = blockIdx.x * 256 + threadIdx.x;  // 64 blocks * 256 = 16384 exactly
    int k = i >> 7, o = i & 127;
    Wqt[o * 128 + k] = __float2bfloat16(Wq[i] * QS);
    Wkt[o * 128 + k] = __float2bfloat16(Wk[i]);
    Wvt[o * 128 + k] = __float2bfloat16(Wv[i] * 0.25f);  // head-mean folded into V
    if (i < 128) {
        bias[i]       = bq[i] * QS;
        bias[128 + i] = bk[i];
        bias[256 + i] = bv[i] * 0.25f;
    }
}

// ---------------------------------------------------------------------------
// Kernel 2: Q/K/V projections via 16x16x32 bf16 MFMA.
//   Qo, Ko: row-major [B*N][128] bf16 (Q pre-scaled by C2/sqrt(128))
//   Vt:     transposed [B][128][N] bf16 (pre-scaled by 0.25)
// ---------------------------------------------------------------------------
__global__ __launch_bounds__(256) void proj_qkv(
        const float* __restrict__ x, const float* __restrict__ cond,
        const __hip_bfloat16* __restrict__ Wqt, const __hip_bfloat16* __restrict__ Wkt,
        const __hip_bfloat16* __restrict__ Wvt, const float* __restrict__ bias,
        __hip_bfloat16* __restrict__ Qo, __hip_bfloat16* __restrict__ Ko,
        __hip_bfloat16* __restrict__ Vt) {
    const int lane = threadIdx.x & 63, wv = threadIdx.x >> 6;
    const int l15 = lane & 15, g = lane >> 4;
    const int row0 = blockIdx.x * 64 + wv * 16;   // 256 blocks x 64 rows

    f32x4 qa[8], ka[8], va[8];
#pragma unroll
    for (int ot = 0; ot < 8; ++ot) {
        float b0 = bias[16 * ot + l15];
        float b1 = bias[128 + 16 * ot + l15];
        float b2 = bias[256 + 16 * ot + l15];
        qa[ot] = (f32x4){b0, b0, b0, b0};
        ka[ot] = (f32x4){b1, b1, b1, b1};
        va[ot] = (f32x4){b2, b2, b2, b2};
    }

    const float* xp = x    + (size_t)(row0 + l15) * 128 + 8 * g;
    const float* cp = cond + (size_t)(row0 + l15) * 128 + 8 * g;
#pragma unroll
    for (int kk = 0; kk < 4; ++kk) {
        float4 x0 = *(const float4*)(xp + 32 * kk);
        float4 x1 = *(const float4*)(xp + 32 * kk + 4);
        float4 c0 = *(const float4*)(cp + 32 * kk);
        float4 c1 = *(const float4*)(cp + 32 * kk + 4);
        bf16x8 xa = pack8(x0, x1);
        bf16x8 ca = pack8(c0, c1);
#pragma unroll
        for (int ot = 0; ot < 8; ++ot) {
            const int wo = (16 * ot + l15) * 128 + 32 * kk + 8 * g;
            qa[ot] = MFMA16(xa, *(const bf16x8*)(Wqt + wo), qa[ot]);
            ka[ot] = MFMA16(ca, *(const bf16x8*)(Wkt + wo), ka[ot]);
            va[ot] = MFMA16(ca, *(const bf16x8*)(Wvt + wo), va[ot]);
        }
    }

    // Q, K row-major stores (C/D layout: row = 4g+r, col = 16ot+l15)
#pragma unroll
    for (int ot = 0; ot < 8; ++ot)
#pragma unroll
        for (int r = 0; r < 4; ++r) {
            size_t idx = (size_t)(row0 + 4 * g + r) * 128 + 16 * ot + l15;
            Qo[idx] = __float2bfloat16(qa[ot][r]);
            Ko[idx] = __float2bfloat16(ka[ot][r]);
        }
    // V transposed store: lane holds 4 consecutive n for fixed d -> dwordx2
    const int bb = row0 >> 11, nn = (row0 & 2047) + 4 * g;
#pragma unroll
    for (int ot = 0; ot < 8; ++ot) {
        uint2 pr;
        pr.x = cvtpk_bf16(va[ot][0], va[ot][1]);
        pr.y = cvtpk_bf16(va[ot][2], va[ot][3]);
        *(uint2*)((unsigned short*)Vt + ((size_t)bb * 128 + 16 * ot + l15) * 2048 + nn) = pr;
    }
}

// ---------------------------------------------------------------------------
// Kernel 3: fused tanh-attention, LDS-staged (R16 = R12 revert -- best
// verified variant: attn_main 76 us, bench 87.06).
// Plateau ledger (R6-R15, all 76-93 us): sync structure (2-bar/1-bar/skew/
// counted-vmcnt), TLP (2-4 blocks/CU), ILP (mask prefetch depth), locality
// (XCD-pinning: FETCH -28%, time flat), topology (split kernels: qk_tanh
// alone = 85 us at 31% VALU) -- every hypothesis falsified. Scattered
// per-lane global V gathers regress 1.6x (R7/R14); uncoalesced atomics
// regress 2x (R13). This structure is the empirical optimum:
// 8 waves, 64q x 1024m per block, 64-m chunks, K+V double-buffered via
// global_load_lds (linear dest, XOR-swizzled source), lgkm mid-barrier,
// vmcnt(0) end-barrier, XCD-pinned batch, coalesced-tile atomics.
// ---------------------------------------------------------------------------
__global__ __launch_bounds__(512) void attn_main(
        const __hip_bfloat16* __restrict__ Q, const __hip_bfloat16* __restrict__ K,
        const __hip_bfloat16* __restrict__ Vt, const float* __restrict__ mask,
        float* __restrict__ out) {
    __shared__ __align__(16) char Kl[2][16384];   // [64 m][256B] per buf
    __shared__ __align__(16) char Vl[2][16384];   // [128 d][128B] per buf
    __shared__ __align__(16) char Al[64 * 144];   // [64 q][72 bf16]

    const int lane = threadIdx.x & 63, w = threadIdx.x >> 6;
    const int l15 = lane & 15, g = lane >> 4;
    const int qw = w & 3, mw = w >> 2, dw = mw;
    // XCD-pinned decomposition: batch = blockIdx & 7 (== XCD under round-robin)
    const int b  = blockIdx.x & 7;
    const int r2 = blockIdx.x >> 3;
    const int qt = r2 & 31;
    const int mh = r2 >> 5;
    const int n0 = qt * 64;
    const int mh0 = mh * 1024;

    const __hip_bfloat16* Qb = Q + ((size_t)b * 2048 + n0 + qw * 16) * 128;
    const char* Kg = (const char*)(K + (size_t)b * 2048 * 128);
    const char* Vg = (const char*)(Vt + (size_t)b * 128 * 2048);
    const float* mrow = mask + ((size_t)b * 2048 + n0 + qw * 16 + l15) * 2048
                        + mh0 + mw * 32 + 4 * g;

    bf16x8 qf[4];
#pragma unroll
    for (int h = 0; h < 4; ++h)
        qf[h] = *(const bf16x8*)(Qb + l15 * 128 + 32 * h + 8 * g);

    f32x4 oacc[4];
#pragma unroll
    for (int dtl = 0; dtl < 4; ++dtl) oacc[dtl] = (f32x4){0.f, 0.f, 0.f, 0.f};
    const f32x4 zero = (f32x4){0.f, 0.f, 0.f, 0.f};

    // ---- staging: 2 K-instr + 2 V-instr per wave (1 KB each, linear LDS) --
    auto STAGE = [&](int m0g, int bi) {
#pragma unroll
        for (int i = 0; i < 2; ++i) {
            const int t = w * 2 + i;
            const int o = t * 1024 + lane * 16;
            const int kr = o >> 8, kc = o & 255;
            gload_lds16(Kg + (size_t)(m0g + kr) * 256 + (kc ^ ((kr & 7) << 4)),
                        &Kl[bi][t * 1024]);
            const int vr = o >> 7, vc = o & 127;
            gload_lds16(Vg + (size_t)vr * 4096 + (size_t)m0g * 2 + (vc ^ ((vr & 7) << 4)),
                        &Vl[bi][t * 1024]);
        }
    };

    // prologue: stage chunk 0, prefetch mask chunk 0
    STAGE(mh0, 0);
    f32x4 mkc0 = *(const f32x4*)(mrow);
    f32x4 mkc1 = *(const f32x4*)(mrow + 16);
    asm volatile("s_waitcnt vmcnt(0)" ::: "memory");
    __builtin_amdgcn_s_barrier();

#pragma unroll 2
    for (int c = 0; c < 16; ++c) {
        const int bi = c & 1;
        const int m0g = mh0 + c * 64;
        // issue next chunk's stage + mask prefetch (stay in flight all chunk)
        if (c < 15) STAGE(m0g + 64, bi ^ 1);
        f32x4 mkn0, mkn1;
        if (c < 15) {
            mkn0 = *(const f32x4*)(mrow + (c + 1) * 64);
            mkn1 = *(const f32x4*)(mrow + (c + 1) * 64 + 16);
        }

        // ---- QK + tanh + A-write (wave's 16q x 32m) ----
#pragma unroll
        for (int st = 0; st < 2; ++st) {
            const int mr = mw * 32 + st * 16 + l15;
            const char* kb = &Kl[bi][mr * 256];
            const int sw = (mr & 7) << 4;
            f32x4 s0 = MFMA16(*(const bf16x8*)(kb + ((g * 16) ^ sw)),       qf[0], zero);
            f32x4 s1 = MFMA16(*(const bf16x8*)(kb + ((64 + g * 16) ^ sw)),  qf[1], zero);
            f32x4 s2 = MFMA16(*(const bf16x8*)(kb + ((128 + g * 16) ^ sw)), qf[2], zero);
            f32x4 s3 = MFMA16(*(const bf16x8*)(kb + ((192 + g * 16) ^ sw)), qf[3], zero);
            const f32x4 mk = st ? mkc1 : mkc0;
            float acd[4];
#pragma unroll
            for (int r = 0; r < 4; ++r) {
                float m2 = mk[r] * C2;
                float e0 = __builtin_amdgcn_exp2f(m2 + s0[r]);
                float e1 = __builtin_amdgcn_exp2f(m2 + s1[r]);
                float e2 = __builtin_amdgcn_exp2f(m2 + s2[r]);
                float e3 = __builtin_amdgcn_exp2f(m2 + s3[r]);
                float rs = __builtin_amdgcn_rcpf(1.f + e0) + __builtin_amdgcn_rcpf(1.f + e1)
                         + __builtin_amdgcn_rcpf(1.f + e2) + __builtin_amdgcn_rcpf(1.f + e3);
                acd[r] = 4.f - 2.f * rs;   // sum_h tanh(...)
            }
            uint2 pk;
            pk.x = cvtpk_bf16(acd[0], acd[1]);
            pk.y = cvtpk_bf16(acd[2], acd[3]);
            *(uint2*)(Al + (qw * 16 + l15) * 144 + (mw * 32 + st * 16 + 4 * g) * 2) = pk;
        }

        // A visible block-wide; do NOT drain vmcnt (stage stays in flight)
        asm volatile("s_waitcnt lgkmcnt(0)" ::: "memory");
        __builtin_amdgcn_s_barrier();

        // ---- PV: wave's 16q x 64d over this chunk's 64 m ----
#pragma unroll
        for (int ks = 0; ks < 2; ++ks) {
            bf16x8 af = *(const bf16x8*)(Al + (qw * 16 + l15) * 144 + (ks * 32 + 8 * g) * 2);
#pragma unroll
            for (int dtl = 0; dtl < 4; ++dtl) {
                const int dr = dw * 64 + dtl * 16 + l15;
                bf16x8 vf = *(const bf16x8*)(
                    &Vl[bi][dr * 128 + ((ks * 64 + g * 16) ^ ((dr & 7) << 4))]);
                oacc[dtl] = MFMA16(af, vf, oacc[dtl]);
            }
        }

        // own stage complete, then joint barrier: everyone staged + reads done
        asm volatile("s_waitcnt vmcnt(0)" ::: "memory");
        __builtin_amdgcn_s_barrier();

        mkc0 = mkn0;
        mkc1 = mkn1;
    }

    // epilogue: per-wave-disjoint 16q x 64d tile; 2 m-half blocks contend
    float* ob = out + ((size_t)b * 2048 + n0 + qw * 16) * 128 + dw * 64;
#pragma unroll
    for (int dtl = 0; dtl < 4; ++dtl)
#pragma unroll
        for (int r = 0; r < 4; ++r)
            unsafeAtomicAdd(&ob[(size_t)(4 * g + r) * 128 + dtl * 16 + l15], oacc[dtl][r]);
}

// ---------------------------------------------------------------------------
extern "C" void kernel_launch(void* const* d_in, const int* in_sizes, int n_in,
                              void* d_out, int out_size, void* d_ws, size_t ws_size,
                              hipStream_t stream) {
    const float* x    = (const float*)d_in[0];
    const float* cond = (const float*)d_in[1];
    // d_in[2] = flags (unused by reference)
    const float* mask = (const float*)d_in[3];
    const float* Wq = (const float*)d_in[4];
    const float* bq = (const float*)d_in[5];
    const float* Wk = (const float*)d_in[6];
    const float* bk = (const float*)d_in[7];
    const float* Wv = (const float*)d_in[8];
    const float* bv = (const float*)d_in[9];
    float* out = (float*)d_out;

    char* ws = (char*)d_ws;
    __hip_bfloat16* Qo  = (__hip_bfloat16*)(ws);                       // 4 MB
    __hip_bfloat16* Ko  = (__hip_bfloat16*)(ws + (4  << 20));          // 4 MB
    __hip_bfloat16* Vt  = (__hip_bfloat16*)(ws + (8  << 20));          // 4 MB
    __hip_bfloat16* Wqt = (__hip_bfloat16*)(ws + (12 << 20));          // 32 KB
    __hip_bfloat16* Wkt = (__hip_bfloat16*)(ws + (12 << 20) + 32768);
    __hip_bfloat16* Wvt = (__hip_bfloat16*)(ws + (12 << 20) + 65536);
    float*          bias = (float*)(ws + (12 << 20) + 98304);          // 1.5 KB

    // out accumulates atomic partials from 2 m-half blocks -> zero it first
    hipMemsetAsync(d_out, 0, (size_t)out_size * sizeof(float), stream);

    prep_weights<<<64, 256, 0, stream>>>(Wq, bq, Wk, bk, Wv, bv, Wqt, Wkt, Wvt, bias);
    proj_qkv<<<256, 256, 0, stream>>>(x, cond, Wqt, Wkt, Wvt, bias, Qo, Ko, Vt);
    attn_main<<<512, 512, 0, stream>>>(Qo, Ko, Vt, mask, out);
}

// Round 17
// 86.722 us; speedup vs baseline: 2.0095x; 1.0043x over previous
//
#include <hip/hip_runtime.h>
#include <hip/hip_bf16.h>

typedef __attribute__((ext_vector_type(4))) float f32x4;
typedef __attribute__((ext_vector_type(8))) short bf16x8;

#define MFMA16(A, B, C) __builtin_amdgcn_mfma_f32_16x16x32_bf16(A, B, C, 0, 0, 0)

// 2*log2(e): tanh(x) = 1 - 2/(1 + 2^(C2*x))
#define C2 2.8853900817779268f
// C2 / sqrt(128), folded into Wq/bq so MFMA output is already exp2-scaled
#define QS (2.8853900817779268f / 11.313708498984761f)

__device__ __forceinline__ unsigned cvtpk_bf16(float lo, float hi) {
    unsigned r;
    asm("v_cvt_pk_bf16_f32 %0, %1, %2" : "=v"(r) : "v"(lo), "v"(hi));
    return r;
}

__device__ __forceinline__ bf16x8 pack8(float4 a, float4 b) {
    union { unsigned u[4]; bf16x8 v; } u;
    u.u[0] = cvtpk_bf16(a.x, a.y);
    u.u[1] = cvtpk_bf16(a.z, a.w);
    u.u[2] = cvtpk_bf16(b.x, b.y);
    u.u[3] = cvtpk_bf16(b.z, b.w);
    return u.v;
}

// async global->LDS, 16B per lane; LDS dest = wave-uniform base + lane*16
__device__ __forceinline__ void gload_lds16(const void* g, void* l) {
    __builtin_amdgcn_global_load_lds(
        (const __attribute__((address_space(1))) unsigned int*)g,
        (__attribute__((address_space(3))) unsigned int*)l, 16, 0, 0);
}

// ---------------------------------------------------------------------------
// Kernel 1: transpose + convert weights to bf16, fold scales, stash biases.
// ---------------------------------------------------------------------------
__global__ void prep_weights(const float* __restrict__ Wq, const float* __restrict__ bq,
                             const float* __restrict__ Wk, const float* __restrict__ bk,
                             const float* __restrict__ Wv, const float* __restrict__ bv,
                             __hip_bfloat16* __restrict__ Wqt, __hip_bfloat16* __restrict__ Wkt,
                             __hip_bfloat16* __restrict__ Wvt, float* __restrict__ bias) {
    int i = blockIdx.x * 256 + threadIdx.x;  // 64 blocks * 256 = 16384 exactly
    int k = i >> 7, o = i & 127;
    Wqt[o * 128 + k] = __float2bfloat16(Wq[i] * QS);
    Wkt[o * 128 + k] = __float2bfloat16(Wk[i]);
    Wvt[o * 128 + k] = __float2bfloat16(Wv[i] * 0.25f);  // head-mean folded into V
    if (i < 128) {
        bias[i]       = bq[i] * QS;
        bias[128 + i] = bk[i];
        bias[256 + i] = bv[i] * 0.25f;
    }
}

// ---------------------------------------------------------------------------
// Kernel 2: Q/K/V projections via 16x16x32 bf16 MFMA.
//   Qo, Ko: row-major [B*N][128] bf16 (Q pre-scaled by C2/sqrt(128))
//   Vt:     transposed [B][128][N] bf16 (pre-scaled by 0.25)
// ---------------------------------------------------------------------------
__global__ __launch_bounds__(256) void proj_qkv(
        const float* __restrict__ x, const float* __restrict__ cond,
        const __hip_bfloat16* __restrict__ Wqt, const __hip_bfloat16* __restrict__ Wkt,
        const __hip_bfloat16* __restrict__ Wvt, const float* __restrict__ bias,
        __hip_bfloat16* __restrict__ Qo, __hip_bfloat16* __restrict__ Ko,
        __hip_bfloat16* __restrict__ Vt) {
    const int lane = threadIdx.x & 63, wv = threadIdx.x >> 6;
    const int l15 = lane & 15, g = lane >> 4;
    const int row0 = blockIdx.x * 64 + wv * 16;   // 256 blocks x 64 rows

    f32x4 qa[8], ka[8], va[8];
#pragma unroll
    for (int ot = 0; ot < 8; ++ot) {
        float b0 = bias[16 * ot + l15];
        float b1 = bias[128 + 16 * ot + l15];
        float b2 = bias[256 + 16 * ot + l15];
        qa[ot] = (f32x4){b0, b0, b0, b0};
        ka[ot] = (f32x4){b1, b1, b1, b1};
        va[ot] = (f32x4){b2, b2, b2, b2};
    }

    const float* xp = x    + (size_t)(row0 + l15) * 128 + 8 * g;
    const float* cp = cond + (size_t)(row0 + l15) * 128 + 8 * g;
#pragma unroll
    for (int kk = 0; kk < 4; ++kk) {
        float4 x0 = *(const float4*)(xp + 32 * kk);
        float4 x1 = *(const float4*)(xp + 32 * kk + 4);
        float4 c0 = *(const float4*)(cp + 32 * kk);
        float4 c1 = *(const float4*)(cp + 32 * kk + 4);
        bf16x8 xa = pack8(x0, x1);
        bf16x8 ca = pack8(c0, c1);
#pragma unroll
        for (int ot = 0; ot < 8; ++ot) {
            const int wo = (16 * ot + l15) * 128 + 32 * kk + 8 * g;
            qa[ot] = MFMA16(xa, *(const bf16x8*)(Wqt + wo), qa[ot]);
            ka[ot] = MFMA16(ca, *(const bf16x8*)(Wkt + wo), ka[ot]);
            va[ot] = MFMA16(ca, *(const bf16x8*)(Wvt + wo), va[ot]);
        }
    }

    // Q, K row-major stores (C/D layout: row = 4g+r, col = 16ot+l15)
#pragma unroll
    for (int ot = 0; ot < 8; ++ot)
#pragma unroll
        for (int r = 0; r < 4; ++r) {
            size_t idx = (size_t)(row0 + 4 * g + r) * 128 + 16 * ot + l15;
            Qo[idx] = __float2bfloat16(qa[ot][r]);
            Ko[idx] = __float2bfloat16(ka[ot][r]);
        }
    // V transposed store: lane holds 4 consecutive n for fixed d -> dwordx2
    const int bb = row0 >> 11, nn = (row0 & 2047) + 4 * g;
#pragma unroll
    for (int ot = 0; ot < 8; ++ot) {
        uint2 pr;
        pr.x = cvtpk_bf16(va[ot][0], va[ot][1]);
        pr.y = cvtpk_bf16(va[ot][2], va[ot][3]);
        *(uint2*)((unsigned short*)Vt + ((size_t)bb * 128 + 16 * ot + l15) * 2048 + nn) = pr;
    }
}

// ---------------------------------------------------------------------------
// Kernel 3: fused tanh-attention, LDS-staged (R17 = R12 + two local edits).
// Structure identical to the verified optimum (R12/R16: 76 us):
// 8 waves, 64q x 1024m per block, 64-m chunks, K+V double-buffered via
// global_load_lds, lgkm mid-barrier, vmcnt(0) end-barrier, XCD-pinned batch,
// coalesced-tile atomics.
// R17 edits (both local, zero structural change):
//  1. __launch_bounds__(512, 4): allocator budget 56 -> 128 VGPR. LDS caps
//     residency at 2 blocks/CU = 4 waves/EU anyway, so no occupancy risk;
//     frees the scheduler to interleave the 16 independent exp2 chains.
//  2. Combined-reciprocal tanh-sum: sum_i 1/(1+e_i) = N/D with one rcp
//     (4 exp2 + 1 rcp + ~15 VALU per score vs 4+4+13): -23% VALU+trans.
//     Overflow-safe: exponent args ~N(0,3^2); D < 2^60 << f32 max.
// ---------------------------------------------------------------------------
__global__ __launch_bounds__(512, 4) void attn_main(
        const __hip_bfloat16* __restrict__ Q, const __hip_bfloat16* __restrict__ K,
        const __hip_bfloat16* __restrict__ Vt, const float* __restrict__ mask,
        float* __restrict__ out) {
    __shared__ __align__(16) char Kl[2][16384];   // [64 m][256B] per buf
    __shared__ __align__(16) char Vl[2][16384];   // [128 d][128B] per buf
    __shared__ __align__(16) char Al[64 * 144];   // [64 q][72 bf16]

    const int lane = threadIdx.x & 63, w = threadIdx.x >> 6;
    const int l15 = lane & 15, g = lane >> 4;
    const int qw = w & 3, mw = w >> 2, dw = mw;
    // XCD-pinned decomposition: batch = blockIdx & 7 (== XCD under round-robin)
    const int b  = blockIdx.x & 7;
    const int r2 = blockIdx.x >> 3;
    const int qt = r2 & 31;
    const int mh = r2 >> 5;
    const int n0 = qt * 64;
    const int mh0 = mh * 1024;

    const __hip_bfloat16* Qb = Q + ((size_t)b * 2048 + n0 + qw * 16) * 128;
    const char* Kg = (const char*)(K + (size_t)b * 2048 * 128);
    const char* Vg = (const char*)(Vt + (size_t)b * 128 * 2048);
    const float* mrow = mask + ((size_t)b * 2048 + n0 + qw * 16 + l15) * 2048
                        + mh0 + mw * 32 + 4 * g;

    bf16x8 qf[4];
#pragma unroll
    for (int h = 0; h < 4; ++h)
        qf[h] = *(const bf16x8*)(Qb + l15 * 128 + 32 * h + 8 * g);

    f32x4 oacc[4];
#pragma unroll
    for (int dtl = 0; dtl < 4; ++dtl) oacc[dtl] = (f32x4){0.f, 0.f, 0.f, 0.f};
    const f32x4 zero = (f32x4){0.f, 0.f, 0.f, 0.f};

    // ---- staging: 2 K-instr + 2 V-instr per wave (1 KB each, linear LDS) --
    auto STAGE = [&](int m0g, int bi) {
#pragma unroll
        for (int i = 0; i < 2; ++i) {
            const int t = w * 2 + i;
            const int o = t * 1024 + lane * 16;
            const int kr = o >> 8, kc = o & 255;
            gload_lds16(Kg + (size_t)(m0g + kr) * 256 + (kc ^ ((kr & 7) << 4)),
                        &Kl[bi][t * 1024]);
            const int vr = o >> 7, vc = o & 127;
            gload_lds16(Vg + (size_t)vr * 4096 + (size_t)m0g * 2 + (vc ^ ((vr & 7) << 4)),
                        &Vl[bi][t * 1024]);
        }
    };

    // prologue: stage chunk 0, prefetch mask chunk 0
    STAGE(mh0, 0);
    f32x4 mkc0 = *(const f32x4*)(mrow);
    f32x4 mkc1 = *(const f32x4*)(mrow + 16);
    asm volatile("s_waitcnt vmcnt(0)" ::: "memory");
    __builtin_amdgcn_s_barrier();

#pragma unroll 2
    for (int c = 0; c < 16; ++c) {
        const int bi = c & 1;
        const int m0g = mh0 + c * 64;
        // issue next chunk's stage + mask prefetch (stay in flight all chunk)
        if (c < 15) STAGE(m0g + 64, bi ^ 1);
        f32x4 mkn0, mkn1;
        if (c < 15) {
            mkn0 = *(const f32x4*)(mrow + (c + 1) * 64);
            mkn1 = *(const f32x4*)(mrow + (c + 1) * 64 + 16);
        }

        // ---- QK + tanh + A-write (wave's 16q x 32m) ----
#pragma unroll
        for (int st = 0; st < 2; ++st) {
            const int mr = mw * 32 + st * 16 + l15;
            const char* kb = &Kl[bi][mr * 256];
            const int sw = (mr & 7) << 4;
            f32x4 s0 = MFMA16(*(const bf16x8*)(kb + ((g * 16) ^ sw)),       qf[0], zero);
            f32x4 s1 = MFMA16(*(const bf16x8*)(kb + ((64 + g * 16) ^ sw)),  qf[1], zero);
            f32x4 s2 = MFMA16(*(const bf16x8*)(kb + ((128 + g * 16) ^ sw)), qf[2], zero);
            f32x4 s3 = MFMA16(*(const bf16x8*)(kb + ((192 + g * 16) ^ sw)), qf[3], zero);
            const f32x4 mk = st ? mkc1 : mkc0;
            float acd[4];
#pragma unroll
            for (int r = 0; r < 4; ++r) {
                // sum_h tanh = 4 - 2 * sum_h 1/(1+e_h); combined reciprocal:
                // sum 1/t_i = N/D, N = sum_i prod_{j!=i} t_j, D = prod t_i.
                float t0 = 1.f + __builtin_amdgcn_exp2f(fmaf(mk[r], C2, s0[r]));
                float t1 = 1.f + __builtin_amdgcn_exp2f(fmaf(mk[r], C2, s1[r]));
                float t2 = 1.f + __builtin_amdgcn_exp2f(fmaf(mk[r], C2, s2[r]));
                float t3 = 1.f + __builtin_amdgcn_exp2f(fmaf(mk[r], C2, s3[r]));
                float p  = t0 * t1, q = t2 * t3;
                float nn = fmaf(t0 + t1, q, (t2 + t3) * p);
                float rs = nn * __builtin_amdgcn_rcpf(p * q);
                acd[r] = fmaf(-2.f, rs, 4.f);
            }
            uint2 pk;
            pk.x = cvtpk_bf16(acd[0], acd[1]);
            pk.y = cvtpk_bf16(acd[2], acd[3]);
            *(uint2*)(Al + (qw * 16 + l15) * 144 + (mw * 32 + st * 16 + 4 * g) * 2) = pk;
        }

        // A visible block-wide; do NOT drain vmcnt (stage stays in flight)
        asm volatile("s_waitcnt lgkmcnt(0)" ::: "memory");
        __builtin_amdgcn_s_barrier();

        // ---- PV: wave's 16q x 64d over this chunk's 64 m ----
#pragma unroll
        for (int ks = 0; ks < 2; ++ks) {
            bf16x8 af = *(const bf16x8*)(Al + (qw * 16 + l15) * 144 + (ks * 32 + 8 * g) * 2);
#pragma unroll
            for (int dtl = 0; dtl < 4; ++dtl) {
                const int dr = dw * 64 + dtl * 16 + l15;
                bf16x8 vf = *(const bf16x8*)(
                    &Vl[bi][dr * 128 + ((ks * 64 + g * 16) ^ ((dr & 7) << 4))]);
                oacc[dtl] = MFMA16(af, vf, oacc[dtl]);
            }
        }

        // own stage complete, then joint barrier: everyone staged + reads done
        asm volatile("s_waitcnt vmcnt(0)" ::: "memory");
        __builtin_amdgcn_s_barrier();

        mkc0 = mkn0;
        mkc1 = mkn1;
    }

    // epilogue: per-wave-disjoint 16q x 64d tile; 2 m-half blocks contend
    float* ob = out + ((size_t)b * 2048 + n0 + qw * 16) * 128 + dw * 64;
#pragma unroll
    for (int dtl = 0; dtl < 4; ++dtl)
#pragma unroll
        for (int r = 0; r < 4; ++r)
            unsafeAtomicAdd(&ob[(size_t)(4 * g + r) * 128 + dtl * 16 + l15], oacc[dtl][r]);
}

// ---------------------------------------------------------------------------
extern "C" void kernel_launch(void* const* d_in, const int* in_sizes, int n_in,
                              void* d_out, int out_size, void* d_ws, size_t ws_size,
                              hipStream_t stream) {
    const float* x    = (const float*)d_in[0];
    const float* cond = (const float*)d_in[1];
    // d_in[2] = flags (unused by reference)
    const float* mask = (const float*)d_in[3];
    const float* Wq = (const float*)d_in[4];
    const float* bq = (const float*)d_in[5];
    const float* Wk = (const float*)d_in[6];
    const float* bk = (const float*)d_in[7];
    const float* Wv = (const float*)d_in[8];
    const float* bv = (const float*)d_in[9];
    float* out = (float*)d_out;

    char* ws = (char*)d_ws;
    __hip_bfloat16* Qo  = (__hip_bfloat16*)(ws);                       // 4 MB
    __hip_bfloat16* Ko  = (__hip_bfloat16*)(ws + (4  << 20));          // 4 MB
    __hip_bfloat16* Vt  = (__hip_bfloat16*)(ws + (8  << 20));          // 4 MB
    __hip_bfloat16* Wqt = (__hip_bfloat16*)(ws + (12 << 20));          // 32 KB
    __hip_bfloat16* Wkt = (__hip_bfloat16*)(ws + (12 << 20) + 32768);
    __hip_bfloat16* Wvt = (__hip_bfloat16*)(ws + (12 << 20) + 65536);
    float*          bias = (float*)(ws + (12 << 20) + 98304);          // 1.5 KB

    // out accumulates atomic partials from 2 m-half blocks -> zero it first
    hipMemsetAsync(d_out, 0, (size_t)out_size * sizeof(float), stream);

    prep_weights<<<64, 256, 0, stream>>>(Wq, bq, Wk, bk, Wv, bv, Wqt, Wkt, Wvt, bias);
    proj_qkv<<<256, 256, 0, stream>>>(x, cond, Wqt, Wkt, Wvt, bias, Qo, Ko, Vt);
    attn_main<<<512, 512, 0, stream>>>(Qo, Ko, Vt, mask, out);
}